// Round 3
// baseline (13039.893 us; speedup 1.0000x reference)
//
#include <hip/hip_runtime.h>
#include <math.h>

// Problem dims
#define B_ 1024
#define T_ 128
#define F_ 128
#define H_ 512

// Output flat offsets (floats): (imputed, CH, h_T, XH, CH, ZH)
#define O_IMP 0
#define O_CH1 16777216
#define O_HT  33554432
#define O_XH  34078720
#define O_CH2 50855936
#define O_ZH  67633152

__device__ __forceinline__ float sigm(float x) { return 1.0f / (1.0f + __expf(-x)); }

// ws layout (floats): hdec0 [B*H] | hdec1 [B*H] | c [B*H] | cc [B*F]
__global__ __launch_bounds__(256) void init_state(float* ws) {
  int i = blockIdx.x * 256 + threadIdx.x;      // 0 .. 262143
  const int n = (B_ * H_) / 4;                 // 131072 float4 per B*H buffer
  float4 z = make_float4(0.f, 0.f, 0.f, 0.f);
  float4* w4 = (float4*)ws;
  if (i < n) w4[i] = z;                        // hdec0
  else       w4[i + n] = z;                    // c region: [2n, 3n)
}

// ---------------- Phase A: per-row chain x_h -> x_c -> z_h -> alpha -> c_h -> c_c ----------------
// grid 256 blocks x 4 rows, 512 threads (8 waves -> 2 waves/SIMD).
// thread = (f = tid&127, rp = tid>>7 -> owns row rp). Register-prefetched weight staging.
__global__ __launch_bounds__(512) void rits_phaseA(
    const float* __restrict__ X, const float* __restrict__ MM, const float* __restrict__ D,
    const float* __restrict__ W_gx, const float* __restrict__ b_gx,
    const float* __restrict__ W_hist, const float* __restrict__ b_hist,
    const float* __restrict__ W_feat, const float* __restrict__ b_feat,
    const float* __restrict__ W_comb, const float* __restrict__ b_comb,
    const float* __restrict__ hdec, float* __restrict__ cc_ws,
    float* __restrict__ out, int t)
{
  __shared__ float hds[4][516];    // h_dec rows (pitch 516 floats = 2064B, 16B aligned)
  __shared__ float wch[128][68];   // weight chunk [row][64k]
  __shared__ float xcs[4][132];    // x_c rows
  __shared__ float gxm[4][260];    // [gamma_x | m] rows (K=256 for alpha)

  const int tid = threadIdx.x;
  const int f = tid & 127;
  const int rp = tid >> 7;         // row 0..3
  const int r0 = blockIdx.x * 4;

  // staging indices for wch: 2048 float4 / 512 threads = 4 each
  const int swrow[1] = {0};  (void)swrow;

  // load h_dec rows (4 x 512 = 512 float4, 1 per thread)
  {
    int row = tid >> 7, c4 = tid & 127;
    *(float4*)&hds[row][c4 * 4] = *(const float4*)&hdec[(r0 + row) * H_ + c4 * 4];
  }

  // ---- x_h = h_dec @ W_hist^T + b_hist   (K=512, 8 chunks of 64) ----
  float xh = b_hist[f];
  float4 pw[4];
  #pragma unroll
  for (int i = 0; i < 4; ++i) {
    int f4 = tid + 512 * i;
    int row = f4 >> 4, c4 = f4 & 15;
    pw[i] = *(const float4*)&W_hist[row * H_ + 0 + c4 * 4];
  }
  for (int kc = 0; kc < 8; ++kc) {
    #pragma unroll
    for (int i = 0; i < 4; ++i) {
      int f4 = tid + 512 * i;
      int row = f4 >> 4, c4 = f4 & 15;
      *(float4*)&wch[row][c4 * 4] = pw[i];
    }
    __syncthreads();
    if (kc < 7) {
      int k0 = (kc + 1) * 64;
      #pragma unroll
      for (int i = 0; i < 4; ++i) {
        int f4 = tid + 512 * i;
        int row = f4 >> 4, c4 = f4 & 15;
        pw[i] = *(const float4*)&W_hist[row * H_ + k0 + c4 * 4];
      }
    }
    int k0 = kc * 64;
    #pragma unroll 4
    for (int k = 0; k < 64; k += 4) {
      float4 w = *(const float4*)&wch[f][k];
      float4 h4 = *(const float4*)&hds[rp][k0 + k];
      xh += w.x * h4.x + w.y * h4.y + w.z * h4.z + w.w * h4.w;
    }
    __syncthreads();
  }

  // elementwise: x_c, gamma_x, stage [gamma_x|m], write XH
  float xv, mv, xcv;
  {
    float wgx = W_gx[f * F_ + f];
    float bgx = b_gx[f];
    int idx = ((r0 + rp) * T_ + t) * F_ + f;
    float x = X[idx], m = MM[idx], d = D[idx];
    xv = x; mv = m;
    float xc = m * x + (1.f - m) * xh;
    xcv = xc;
    xcs[rp][f] = xc;
    gxm[rp][f] = __expf(-fmaxf(d * wgx + bgx, 0.f));
    gxm[rp][F_ + f] = m;
    out[O_XH + idx] = xh;
  }
  __syncthreads();

  // ---- z_h = x_c @ Wfeat_od^T + b_feat  (K=128, 2 chunks; diagonal removed) ----
  float zh = b_feat[f] - xcv * W_feat[f * F_ + f];
  #pragma unroll
  for (int i = 0; i < 4; ++i) {
    int f4 = tid + 512 * i;
    int row = f4 >> 4, c4 = f4 & 15;
    pw[i] = *(const float4*)&W_feat[row * F_ + 0 + c4 * 4];
  }
  for (int kc = 0; kc < 2; ++kc) {
    #pragma unroll
    for (int i = 0; i < 4; ++i) {
      int f4 = tid + 512 * i;
      int row = f4 >> 4, c4 = f4 & 15;
      *(float4*)&wch[row][c4 * 4] = pw[i];
    }
    __syncthreads();
    if (kc < 1) {
      #pragma unroll
      for (int i = 0; i < 4; ++i) {
        int f4 = tid + 512 * i;
        int row = f4 >> 4, c4 = f4 & 15;
        pw[i] = *(const float4*)&W_feat[row * F_ + 64 + c4 * 4];
      }
    }
    int k0 = kc * 64;
    #pragma unroll 4
    for (int k = 0; k < 64; k += 4) {
      float4 w = *(const float4*)&wch[f][k];
      float4 c4v = *(const float4*)&xcs[rp][k0 + k];
      zh += w.x * c4v.x + w.y * c4v.y + w.z * c4v.z + w.w * c4v.w;
    }
    __syncthreads();
  }

  // ---- alpha = sigmoid([gamma_x|m] @ W_comb^T + b_comb)  (K=256, 4 chunks) ----
  float al = b_comb[f];
  #pragma unroll
  for (int i = 0; i < 4; ++i) {
    int f4 = tid + 512 * i;
    int row = f4 >> 4, c4 = f4 & 15;
    pw[i] = *(const float4*)&W_comb[row * 256 + 0 + c4 * 4];
  }
  for (int kc = 0; kc < 4; ++kc) {
    #pragma unroll
    for (int i = 0; i < 4; ++i) {
      int f4 = tid + 512 * i;
      int row = f4 >> 4, c4 = f4 & 15;
      *(float4*)&wch[row][c4 * 4] = pw[i];
    }
    __syncthreads();
    if (kc < 3) {
      int k0 = (kc + 1) * 64;
      #pragma unroll
      for (int i = 0; i < 4; ++i) {
        int f4 = tid + 512 * i;
        int row = f4 >> 4, c4 = f4 & 15;
        pw[i] = *(const float4*)&W_comb[row * 256 + k0 + c4 * 4];
      }
    }
    int k0 = kc * 64;
    #pragma unroll 4
    for (int k = 0; k < 64; k += 4) {
      float4 w = *(const float4*)&wch[f][k];
      float4 g4 = *(const float4*)&gxm[rp][k0 + k];
      al += w.x * g4.x + w.y * g4.y + w.z * g4.z + w.w * g4.w;
    }
    __syncthreads();
  }

  // c_h, c_c (== imputed), outputs
  {
    int idx = ((r0 + rp) * T_ + t) * F_ + f;
    float a = sigm(al);
    float ch = a * zh + (1.f - a) * xh;
    float cc = mv * xv + (1.f - mv) * ch;
    out[O_IMP + idx] = cc;
    out[O_CH1 + idx] = ch;
    out[O_CH2 + idx] = ch;
    out[O_ZH  + idx] = zh;
    cc_ws[(r0 + rp) * F_ + f] = cc;
  }
}

// ---------------- Phase B: gates GEMM (K=768) + LSTM + fused gamma_h[t+1]*decay ----------------
// grid (16,16): 64-row x 32-hcol tile (=> 128 gate cols). 512 threads (2 waves/SIMD).
// thread: tx=tid&31 -> cols 4tx..4tx+3; ty=tid>>5 (0..15) -> rows 4ty..4ty+3. acc[4][4].
__global__ __launch_bounds__(512) void rits_phaseB(
    const float* __restrict__ MM, const float* __restrict__ D,
    const float* __restrict__ W_gh, const float* __restrict__ b_gh,
    const float* __restrict__ W_ih, const float* __restrict__ W_hh,
    const float* __restrict__ b_ih, const float* __restrict__ b_hh,
    const float* __restrict__ cc_ws, const float* __restrict__ hdec_in,
    float* __restrict__ hdec_out, float* __restrict__ c_ws,
    float* __restrict__ out, int t)
{
  __shared__ float Ash[32][68];     // A chunk, [k][row]
  __shared__ float Wsh[32][132];    // W chunk, [k][col]
  __shared__ float gsh[64][132];    // gates tile; reused for d[t+1] tile
  __shared__ float wgsh[32][132];   // W_gh rows for this hcol tile

  const int tid = threadIdx.x;
  const int tx = tid & 31, ty = tid >> 5;
  const int r0 = blockIdx.x * 64;
  const int c0 = blockIdx.y * 32;

  // stage W_gh tile (32 hcols x 128 = 1024 float4, 2 per thread)
  #pragma unroll
  for (int i = 0; i < 2; ++i) {
    int f4 = tid + 512 * i;
    int hr = f4 >> 5, c4 = f4 & 31;
    *(float4*)&wgsh[hr][c4 * 4] = *(const float4*)&W_gh[(c0 + hr) * F_ + c4 * 4];
  }

  // staging maps
  const int ar = tid >> 3;            // 0..63  A row
  const int akq = (tid & 7) * 4;      // k sub-offset (1 float4)
  const int wcol = tid >> 2;          // 0..127 W col
  const int wkq = (tid & 3) * 8;      // k sub-offset (2 float4)
  const int wg = (wcol >> 5) * H_ + c0 + (wcol & 31);

  // prefetch chunk 0
  float4 pa, pw0, pw1;
  {
    pa = *(const float4*)&cc_ws[(r0 + ar) * F_ + akq];
    const float* q = &W_ih[wg * 256 + wkq];
    pw0 = *(const float4*)q; pw1 = *(const float4*)(q + 4);
  }

  float acc[4][4];
  #pragma unroll
  for (int i = 0; i < 4; ++i)
    #pragma unroll
    for (int j = 0; j < 4; ++j) acc[i][j] = 0.f;

  for (int kc = 0; kc < 24; ++kc) {
    // write prefetched regs -> LDS
    {
      Ash[akq + 0][ar] = pa.x; Ash[akq + 1][ar] = pa.y;
      Ash[akq + 2][ar] = pa.z; Ash[akq + 3][ar] = pa.w;
      float wt[8] = {pw0.x, pw0.y, pw0.z, pw0.w, pw1.x, pw1.y, pw1.z, pw1.w};
      #pragma unroll
      for (int j = 0; j < 8; ++j) Wsh[wkq + j][wcol] = wt[j];
    }
    __syncthreads();
    // issue next chunk's loads; vmcnt wait lands at next iteration's LDS write
    if (kc < 23) {
      int k0 = (kc + 1) * 32;
      const float* p;
      if (k0 < 128)      p = &cc_ws[(r0 + ar) * F_ + k0 + akq];
      else if (k0 < 256) p = &MM[((r0 + ar) * T_ + t) * F_ + (k0 - 128) + akq];
      else               p = &hdec_in[(r0 + ar) * H_ + (k0 - 256) + akq];
      pa = *(const float4*)p;
      const float* q = (k0 < 256) ? &W_ih[wg * 256 + k0 + wkq]
                                  : &W_hh[wg * H_ + (k0 - 256) + wkq];
      pw0 = *(const float4*)q; pw1 = *(const float4*)(q + 4);
    }
    #pragma unroll 4
    for (int kk = 0; kk < 32; ++kk) {
      const float4 a = *(const float4*)&Ash[kk][4 * ty];
      const float4 w = *(const float4*)&Wsh[kk][4 * tx];
      const float av[4] = {a.x, a.y, a.z, a.w};
      #pragma unroll
      for (int i = 0; i < 4; ++i) {
        acc[i][0] = fmaf(av[i], w.x, acc[i][0]);
        acc[i][1] = fmaf(av[i], w.y, acc[i][1]);
        acc[i][2] = fmaf(av[i], w.z, acc[i][2]);
        acc[i][3] = fmaf(av[i], w.w, acc[i][3]);
      }
    }
    __syncthreads();
  }

  // add biases, park gates in LDS for quadrant exchange
  #pragma unroll
  for (int j = 0; j < 4; ++j) {
    int cl = 4 * tx + j;
    int g = (cl >> 5) * H_ + c0 + (cl & 31);
    float bia = b_ih[g] + b_hh[g];
    #pragma unroll
    for (int i = 0; i < 4; ++i) gsh[4 * ty + i][cl] = acc[i][j] + bia;
  }
  __syncthreads();

  // LSTM update: thread = (hl = tid&31, rg = tid>>5 -> rows 4rg..4rg+3)
  const int hl = tid & 31;
  const int rg = tid >> 5;
  float hnew[4];
  #pragma unroll
  for (int i = 0; i < 4; ++i) {
    int r = 4 * rg + i;
    float ig = gsh[r][hl];
    float fg = gsh[r][32 + hl];
    float gg = gsh[r][64 + hl];
    float og = gsh[r][96 + hl];
    int cidx = (r0 + r) * H_ + c0 + hl;
    float cn = sigm(fg) * c_ws[cidx] + sigm(ig) * tanhf(gg);
    c_ws[cidx] = cn;
    hnew[i] = sigm(og) * tanhf(cn);
  }
  __syncthreads();

  if (t == T_ - 1) {
    #pragma unroll
    for (int i = 0; i < 4; ++i) {
      int r = 4 * rg + i;
      out[O_HT + (r0 + r) * H_ + c0 + hl] = hnew[i];
    }
  } else {
    // stage d[:, t+1, :] tile into gsh (reuse): 64x128 = 2048 float4, 4 per thread
    #pragma unroll
    for (int i = 0; i < 4; ++i) {
      int f4 = tid + 512 * i;
      int r = f4 >> 5, c4 = f4 & 31;
      *(float4*)&gsh[r][c4 * 4] = *(const float4*)&D[((r0 + r) * T_ + (t + 1)) * F_ + c4 * 4];
    }
    __syncthreads();
    float bg = b_gh[c0 + hl];
    float dot0[4];
    #pragma unroll
    for (int i = 0; i < 4; ++i) dot0[i] = 0.f;
    for (int kb = 0; kb < 128; kb += 16) {
      const float4 w0 = *(const float4*)&wgsh[hl][kb];
      const float4 w1 = *(const float4*)&wgsh[hl][kb + 4];
      const float4 w2 = *(const float4*)&wgsh[hl][kb + 8];
      const float4 w3 = *(const float4*)&wgsh[hl][kb + 12];
      #pragma unroll
      for (int i = 0; i < 4; ++i) {
        const float* dr = &gsh[4 * rg + i][kb];
        const float4 d0 = *(const float4*)dr;
        const float4 d1 = *(const float4*)(dr + 4);
        const float4 d2 = *(const float4*)(dr + 8);
        const float4 d3 = *(const float4*)(dr + 12);
        dot0[i] += w0.x * d0.x + w0.y * d0.y + w0.z * d0.z + w0.w * d0.w
                 + w1.x * d1.x + w1.y * d1.y + w1.z * d1.z + w1.w * d1.w
                 + w2.x * d2.x + w2.y * d2.y + w2.z * d2.z + w2.w * d2.w
                 + w3.x * d3.x + w3.y * d3.y + w3.z * d3.z + w3.w * d3.w;
      }
    }
    #pragma unroll
    for (int i = 0; i < 4; ++i) {
      int r = 4 * rg + i;
      float gam = __expf(-fmaxf(dot0[i] + bg, 0.f));
      hdec_out[(r0 + r) * H_ + c0 + hl] = hnew[i] * gam;
    }
  }
}

extern "C" void kernel_launch(void* const* d_in, const int* in_sizes, int n_in,
                              void* d_out, int out_size, void* d_ws, size_t ws_size,
                              hipStream_t stream) {
  const float* X      = (const float*)d_in[0];
  const float* MM     = (const float*)d_in[1];
  const float* D      = (const float*)d_in[2];
  const float* W_gh   = (const float*)d_in[3];
  const float* b_gh   = (const float*)d_in[4];
  const float* W_gx   = (const float*)d_in[5];
  const float* b_gx   = (const float*)d_in[6];
  const float* W_hist = (const float*)d_in[7];
  const float* b_hist = (const float*)d_in[8];
  const float* W_feat = (const float*)d_in[9];
  const float* b_feat = (const float*)d_in[10];
  const float* W_comb = (const float*)d_in[11];
  const float* b_comb = (const float*)d_in[12];
  const float* W_ih   = (const float*)d_in[13];
  const float* W_hh   = (const float*)d_in[14];
  const float* b_ih   = (const float*)d_in[15];
  const float* b_hh   = (const float*)d_in[16];

  float* out = (float*)d_out;
  float* ws = (float*)d_ws;
  float* hd0 = ws;                       // h_dec ping
  float* hd1 = ws + B_ * H_;             // h_dec pong
  float* cst = ws + 2 * B_ * H_;         // c state
  float* ccb = ws + 3 * B_ * H_;         // c_c buffer

  init_state<<<dim3(1024), dim3(256), 0, stream>>>(ws);

  for (int t = 0; t < T_; ++t) {
    float* hin  = (t & 1) ? hd1 : hd0;
    float* hout = (t & 1) ? hd0 : hd1;
    rits_phaseA<<<dim3(256), dim3(512), 0, stream>>>(
        X, MM, D, W_gx, b_gx, W_hist, b_hist, W_feat, b_feat, W_comb, b_comb,
        hin, ccb, out, t);
    rits_phaseB<<<dim3(16, 16), dim3(512), 0, stream>>>(
        MM, D, W_gh, b_gh, W_ih, W_hh, b_ih, b_hh,
        ccb, hin, hout, cst, out, t);
  }
}